// Round 15
// baseline (151.131 us; speedup 1.0000x reference)
//
#include <hip/hip_runtime.h>
#include <stdint.h>
#include <math.h>

#define NOPS 37

struct Ops37 {
    int type[NOPS];  // 0 rx, 1 ry, 2 rz, 3 cnot, 4 H, 5 SX
    int a[NOPS];     // wire (rot/H/SX) or control (cnot)
    int b[NOPS];     // target (cnot), else -1
};

// ---------------------------------------------------------------------------
// Host-side exact replication of np.random.default_rng(42) for _random_ops().
// VERIFIED PASSING (round 3). DO NOT TOUCH.
// ---------------------------------------------------------------------------
static void build_ops_host(Ops37* ops) {
    uint32_t pool[4];
    uint32_t hc = 0x43b0d7e5u;  // INIT_A
    auto hmix = [&hc](uint32_t value) -> uint32_t {
        value ^= hc;
        hc *= 0x931e8875u;      // MULT_A
        value *= hc;
        value ^= value >> 16;
        return value;
    };
    auto mixf = [](uint32_t x, uint32_t y) -> uint32_t {
        uint32_t r = (x * 0xca01f9ddu) - (y * 0x4973f715u);  // SUBTRACTION
        r ^= r >> 16;
        return r;
    };
    pool[0] = hmix(42u);
    for (int i = 1; i < 4; i++) pool[i] = hmix(0u);
    for (int s = 0; s < 4; s++)
        for (int d = 0; d < 4; d++)
            if (s != d) pool[d] = mixf(pool[d], hmix(pool[s]));

    uint32_t st[8];
    {
        uint32_t hcb = 0x8b51f9ddu;  // INIT_B
        for (int i = 0; i < 8; i++) {
            uint32_t dv = pool[i & 3];
            dv ^= hcb;
            hcb *= 0x58f38dedu;      // MULT_B
            dv *= hcb;
            dv ^= dv >> 16;
            st[i] = dv;
        }
    }
    typedef __uint128_t u128;
    const uint64_t v0 = (uint64_t)st[0] | ((uint64_t)st[1] << 32);
    const uint64_t v1 = (uint64_t)st[2] | ((uint64_t)st[3] << 32);
    const uint64_t v2 = (uint64_t)st[4] | ((uint64_t)st[5] << 32);
    const uint64_t v3 = (uint64_t)st[6] | ((uint64_t)st[7] << 32);
    const u128 initstate = (((u128)v0) << 64) | v1;
    const u128 initseq   = (((u128)v2) << 64) | v3;
    const u128 MULT = (((u128)0x2360ed051fc65da4ULL) << 64) | 0x4385df649fccf645ULL;

    u128 state = 0;
    const u128 inc = (initseq << 1) | 1;
    state = state * MULT + inc;
    state += initstate;
    state = state * MULT + inc;

    bool has32 = false;
    uint32_t cached = 0;
    auto next64 = [&]() -> uint64_t {
        state = state * MULT + inc;
        uint64_t hi = (uint64_t)(state >> 64);
        uint64_t lo = (uint64_t)state;
        unsigned rot = (unsigned)(state >> 122) & 63u;
        uint64_t v = hi ^ lo;
        return (v >> rot) | (v << ((64u - rot) & 63u));
    };
    auto next32 = [&]() -> uint32_t {
        if (has32) { has32 = false; return cached; }
        uint64_t n = next64();
        has32 = true;
        cached = (uint32_t)(n >> 32);
        return (uint32_t)n;
    };
    auto lem = [&](uint32_t rng) -> uint32_t {
        const uint32_t rng_excl = rng + 1u;
        uint64_t m = (uint64_t)next32() * (uint64_t)rng_excl;
        uint32_t leftover = (uint32_t)m;
        if (leftover < rng_excl) {
            const uint32_t threshold = (0xFFFFFFFFu - rng) % rng_excl;
            while (leftover < threshold) {
                m = (uint64_t)next32() * (uint64_t)rng_excl;
                leftover = (uint32_t)m;
            }
        }
        return (uint32_t)(m >> 32);
    };

    for (int k = 0; k < 30; k++) {
        uint32_t g = lem(3);
        if (g == 3u) {
            uint32_t i0 = lem(2);
            uint32_t vv = lem(3);
            uint32_t i1 = (vv == i0) ? 3u : vv;
            uint32_t j = lem(1);
            if (j == 0u) { uint32_t t = i0; i0 = i1; i1 = t; }
            ops->type[k] = 3; ops->a[k] = (int)i0; ops->b[k] = (int)i1;
        } else {
            uint32_t w = lem(3);
            ops->type[k] = (int)g; ops->a[k] = (int)w; ops->b[k] = -1;
        }
    }
    ops->type[30] = 0; ops->a[30] = 0; ops->b[30] = -1;
    ops->type[31] = 1; ops->a[31] = 1; ops->b[31] = -1;
    ops->type[32] = 2; ops->a[32] = 2; ops->b[32] = -1;
    ops->type[33] = 3; ops->a[33] = 0; ops->b[33] = 3;
    ops->type[34] = 4; ops->a[34] = 3; ops->b[34] = -1;
    ops->type[35] = 5; ops->a[35] = 2; ops->b[35] = -1;
    ops->type[36] = 3; ops->a[36] = 3; ops->b[36] = 0;
}

// ---------------------------------------------------------------------------
// Kernel 0: build the fixed 16x16 unitary U (post-encoding circuit). fp32.
// ---------------------------------------------------------------------------
__global__ __launch_bounds__(64) void build_u_kernel(
        const float* __restrict__ rl, const float* __restrict__ qrx,
        const float* __restrict__ qry, const float* __restrict__ qrz,
        float* __restrict__ Uout, Ops37 ops) {
    int j = threadIdx.x;
    if (j >= 16) return;
    float cr[16], ci[16];
    for (int i = 0; i < 16; i++) { cr[i] = (i == j) ? 1.f : 0.f; ci[i] = 0.f; }
    for (int k = 0; k < NOPS; k++) {
        int t = ops.type[k];
        if (t == 3) {
            int mc = 8 >> ops.a[k], mt = 8 >> ops.b[k];
            for (int i = 0; i < 16; i++) {
                if ((i & mc) && !(i & mt)) {
                    int i2 = i | mt;
                    float tr = cr[i], ti = ci[i];
                    cr[i] = cr[i2]; ci[i] = ci[i2];
                    cr[i2] = tr;    ci[i2] = ti;
                }
            }
        } else {
            float g00r, g00i, g01r, g01i, g10r, g10i, g11r, g11i;
            if (t == 4) {
                const float r = 0.70710678118654752440f;
                g00r = r; g00i = 0; g01r = r;  g01i = 0;
                g10r = r; g10i = 0; g11r = -r; g11i = 0;
            } else if (t == 5) {
                g00r = 0.5f; g00i = 0.5f;  g01r = 0.5f; g01i = -0.5f;
                g10r = 0.5f; g10i = -0.5f; g11r = 0.5f; g11i = 0.5f;
            } else {
                float th = (k < 30) ? rl[k]
                         : (k == 30 ? qrx[0] : (k == 31 ? qry[0] : qrz[0]));
                float c = cosf(0.5f * th), s = sinf(0.5f * th);
                if (t == 0) {
                    g00r = c; g00i = 0;  g01r = 0; g01i = -s;
                    g10r = 0; g10i = -s; g11r = c; g11i = 0;
                } else if (t == 1) {
                    g00r = c; g00i = 0; g01r = -s; g01i = 0;
                    g10r = s; g10i = 0; g11r = c;  g11i = 0;
                } else {
                    g00r = c; g00i = -s; g01r = 0; g01i = 0;
                    g10r = 0; g10i = 0;  g11r = c; g11i = s;
                }
            }
            int m = 8 >> ops.a[k];
            for (int i = 0; i < 16; i++) {
                if (!(i & m)) {
                    int i2 = i | m;
                    float ar = cr[i], ai = ci[i], br = cr[i2], bi = ci[i2];
                    cr[i]  = g00r * ar - g00i * ai + g01r * br - g01i * bi;
                    ci[i]  = g00r * ai + g00i * ar + g01r * bi + g01i * br;
                    cr[i2] = g10r * ar - g10i * ai + g11r * br - g11i * bi;
                    ci[i2] = g10r * ai + g10i * ar + g11r * bi + g11i * br;
                }
            }
        }
    }
    for (int i = 0; i < 16; i++) {
        Uout[2 * (i * 16 + j)]     = cr[i];
        Uout[2 * (i * 16 + j) + 1] = ci[i];
    }
}

// ---------------------------------------------------------------------------
// Kernel 1: fused per-sample forward. EXACT round-13 kernel (97us, 48 VGPR,
// conflicts 5.2e5, VALUBusy 72%). Round-14's float2/pkfma conv2 REVERTED
// (neutral-to-worse: +4 VGPR, -7% occupancy, no issue-rate win).
// Busy-time invariant (r10-r14): VALU busy ~70us regardless of occupancy —
// the kernel is ISSUE-COUNT-bound; only instruction reduction helps.
// LDS (floats): XP 30x34 [0,1020) reused as h2[784]; H1 8x292 [1020,3356);
// RED[8] FEAT[4] PSI[32] PV[16]. 13.7 KB -> 11 blocks/CU.
// ---------------------------------------------------------------------------
#define XPo   0
#define H2o   0
#define H1o   1020
#define REDo  3356
#define FEATo 3364
#define PSIo  3368
#define PVo   3400
#define SMSZ  3416

#define H1CS  292   // channel stride (= 4 mod 32)
#define H1RS  18    // row stride (bank start 4*py, 7 distinct)

__global__ __launch_bounds__(128) void fused_fwd_kernel(
        const float* __restrict__ x,
        const float* __restrict__ c1w, const float* __restrict__ c1b,
        const float* __restrict__ c2w, const float* __restrict__ c2b,
        const float* __restrict__ fcw, const float* __restrict__ fcb,
        const float* __restrict__ Ug, float* __restrict__ exps) {
    __shared__ __align__(16) float SM[SMSZ];
    const int tid = threadIdx.x;
    const int bidx = blockIdx.x;

    // ---- stage x (zero-padded 30x34); zero H1 borders only ----
    {
        const float* xb = x + (size_t)bidx * 784;
        for (int i = tid; i < 1020; i += 128) {
            int r = i / 34, c = i - r * 34;
            float v = 0.f;
            if (r >= 1 && r <= 28 && c >= 1 && c <= 28) v = xb[(r - 1) * 28 + (c - 1)];
            SM[XPo + i] = v;
        }
    }
    for (int i = tid; i < 480; i += 128) {
        int ch = i / 60, j = i - ch * 60;
        int row, col;
        if (j < 16)      { row = 0;  col = j; }
        else if (j < 32) { row = 15; col = j - 16; }
        else             { row = 1 + ((j - 32) >> 1); col = ((j - 32) & 1) * 15; }
        SM[H1o + ch * H1CS + row * H1RS + col] = 0.f;
    }
    __syncthreads();

    // ---- conv1 + relu + pool ----
    {
        const int c    = tid & 7;
        const int pos0 = tid >> 3;
        float wv[9];
        #pragma unroll
        for (int t = 0; t < 9; t++) wv[t] = c1w[c * 9 + t];
        const float bb = c1b[c];
        for (int pos = pos0; pos < 98; pos += 16) {
            int py = pos / 7, pxp = pos - py * 7;
            float P[4][6];
            #pragma unroll
            for (int r = 0; r < 4; r++) {
                const float2 a  = *(const float2*)&SM[XPo + (2 * py + r) * 34 + 4 * pxp];
                const float2 b_ = *(const float2*)&SM[XPo + (2 * py + r) * 34 + 4 * pxp + 2];
                const float2 c_ = *(const float2*)&SM[XPo + (2 * py + r) * 34 + 4 * pxp + 4];
                P[r][0] = a.x; P[r][1] = a.y; P[r][2] = b_.x;
                P[r][3] = b_.y; P[r][4] = c_.x; P[r][5] = c_.y;
            }
            #pragma unroll
            for (int half = 0; half < 2; half++) {
                float m = -3.4e38f;
                #pragma unroll
                for (int dy = 0; dy < 2; dy++)
                    #pragma unroll
                    for (int dx = 0; dx < 2; dx++) {
                        float acc = 0.f;
                        #pragma unroll
                        for (int ky = 0; ky < 3; ky++)
                            #pragma unroll
                            for (int kx = 0; kx < 3; kx++)
                                acc = fmaf(P[dy + ky][2 * half + dx + kx], wv[ky * 3 + kx], acc);
                        m = fmaxf(m, acc);
                    }
                SM[H1o + c * H1CS + (py + 1) * H1RS + (2 * pxp + half + 1)] = fmaxf(m + bb, 0.f);
            }
        }
    }
    __syncthreads();

    // ---- conv2 + relu + pool ----
    if (tid < 112) {
        int c2 = tid / 7, py = tid - (tid / 7) * 7;
        float acc[7][4];
        #pragma unroll
        for (int px = 0; px < 7; px++)
            #pragma unroll
            for (int s = 0; s < 4; s++) acc[px][s] = 0.f;
        for (int c1 = 0; c1 < 8; c1++) {   // rolled: keeps VGPR ~48
            float R[4][16];
            #pragma unroll
            for (int r = 0; r < 4; r++) {
                #pragma unroll
                for (int q = 0; q < 8; q++) {
                    const float2 v = *(const float2*)&SM[H1o + c1 * H1CS + (2 * py + r) * H1RS + 2 * q];
                    R[r][2 * q] = v.x; R[r][2 * q + 1] = v.y;
                }
            }
            float w[9];
            #pragma unroll
            for (int t = 0; t < 9; t++) w[t] = c2w[(c2 * 8 + c1) * 9 + t];
            #pragma unroll
            for (int px = 0; px < 7; px++)
                #pragma unroll
                for (int dy = 0; dy < 2; dy++)
                    #pragma unroll
                    for (int dx = 0; dx < 2; dx++) {
                        float a = acc[px][dy * 2 + dx];
                        #pragma unroll
                        for (int ky = 0; ky < 3; ky++)
                            #pragma unroll
                            for (int kx = 0; kx < 3; kx++)
                                a = fmaf(R[dy + ky][2 * px + dx + kx], w[ky * 3 + kx], a);
                        acc[px][dy * 2 + dx] = a;
                    }
        }
        const float bb = c2b[c2];
        #pragma unroll
        for (int px = 0; px < 7; px++) {
            float m = fmaxf(fmaxf(acc[px][0], acc[px][1]), fmaxf(acc[px][2], acc[px][3]));
            SM[H2o + c2 * 49 + py * 7 + px] = fmaxf(m + bb, 0.f);
        }
    }
    __syncthreads();

    // ---- fc rows 0..3: shfl reduction ----
    {
        float a0 = 0.f, a1 = 0.f, a2 = 0.f, a3 = 0.f;
        for (int j = tid; j < 784; j += 128) {
            float h = SM[H2o + j];
            a0 = fmaf(h, fcw[j],        a0);
            a1 = fmaf(h, fcw[784 + j],  a1);
            a2 = fmaf(h, fcw[1568 + j], a2);
            a3 = fmaf(h, fcw[2352 + j], a3);
        }
        #pragma unroll
        for (int off = 32; off > 0; off >>= 1) {
            a0 += __shfl_down(a0, off);
            a1 += __shfl_down(a1, off);
            a2 += __shfl_down(a2, off);
            a3 += __shfl_down(a3, off);
        }
        if ((tid & 63) == 0) {
            int wid = tid >> 6;
            SM[REDo + wid * 4 + 0] = a0;
            SM[REDo + wid * 4 + 1] = a1;
            SM[REDo + wid * 4 + 2] = a2;
            SM[REDo + wid * 4 + 3] = a3;
        }
    }
    __syncthreads();
    if (tid < 4)
        SM[FEATo + tid] = fmaxf(SM[REDo + tid] + SM[REDo + 4 + tid] + fcb[tid], 0.f);
    __syncthreads();

    // ---- quantum circuit ----
    if (tid < 16) {
        int j = tid;
        float re = 1.f, im = 0.f;
        #pragma unroll
        for (int w = 0; w < 4; w++) {
            float half = 0.5f * SM[FEATo + w];
            float cc = cosf(half), ss = sinf(half);
            if ((j >> (3 - w)) & 1) {
                float nr = ss * im, ni = -ss * re;
                re = nr; im = ni;
            } else {
                re *= cc; im *= cc;
            }
        }
        SM[PSIo + 2 * j] = re; SM[PSIo + 2 * j + 1] = im;
    }
    __syncthreads();
    if (tid < 16) {
        int r = tid;
        float ar = 0.f, ai = 0.f;
        const float2* U2 = (const float2*)Ug;
        #pragma unroll
        for (int j2 = 0; j2 < 16; j2++) {
            float2 u = U2[r * 16 + j2];
            float pr = SM[PSIo + 2 * j2], pi = SM[PSIo + 2 * j2 + 1];
            ar += u.x * pr - u.y * pi;
            ai += u.x * pi + u.y * pr;
        }
        SM[PVo + r] = ar * ar + ai * ai;
    }
    __syncthreads();
    if (tid < 4) {
        int w = tid, msk = 8 >> w;
        float e = 0.f;
        #pragma unroll
        for (int r = 0; r < 16; r++) {
            float p = SM[PVo + r];
            e += (r & msk) ? -p : p;
        }
        exps[(size_t)bidx * 4 + w] = e;
    }
}

// ---------------------------------------------------------------------------
// Kernel 2: single-dispatch BN + output. 32 blocks x 256. Each block
// REDUNDANTLY fp64-reduces ALL B exps in identical order (deterministic, no
// atomics, no cross-block dependency — r12 lesson), computes {A0..A3, C},
// then writes its 256-sample output slice. Replaces bn_part + out_final
// (one fewer dispatch boundary; 4MB redundant L2 reads ~ 0.1us of BW).
// ---------------------------------------------------------------------------
__global__ __launch_bounds__(256) void out_all_kernel(
        const float* __restrict__ exps,
        const float* __restrict__ gamma, const float* __restrict__ beta,
        const float* __restrict__ ow, const float* __restrict__ ob,
        float* __restrict__ out, int B) {
    const int tid = threadIdx.x;
    const float4* e4 = (const float4*)exps;
    double s0 = 0, s1 = 0, s2 = 0, s3 = 0, q0 = 0, q1 = 0, q2 = 0, q3 = 0;
    for (int i = tid; i < B; i += 256) {   // full range in EVERY block
        float4 e = e4[i];
        s0 += e.x; q0 += (double)e.x * e.x;
        s1 += e.y; q1 += (double)e.y * e.y;
        s2 += e.z; q2 += (double)e.z * e.z;
        s3 += e.w; q3 += (double)e.w * e.w;
    }
    __shared__ double red[8][256];
    __shared__ float stats_s[5];
    red[0][tid] = s0; red[1][tid] = s1; red[2][tid] = s2; red[3][tid] = s3;
    red[4][tid] = q0; red[5][tid] = q1; red[6][tid] = q2; red[7][tid] = q3;
    __syncthreads();
    for (int st = 128; st > 0; st >>= 1) {
        if (tid < st)
            for (int k = 0; k < 8; k++) red[k][tid] += red[k][tid + st];
        __syncthreads();
    }
    if (tid == 0) {
        double C = (double)ob[0];
        for (int w = 0; w < 4; w++) {
            double mean = red[w][0] / (double)B;
            double var  = red[4 + w][0] / (double)B - mean * mean;
            double inv  = 1.0 / sqrt(var + 1e-5);
            double scale = (double)gamma[w] * inv;
            stats_s[w] = (float)(scale * (double)ow[w]);
            C += ((double)beta[w] - mean * scale) * (double)ow[w];
        }
        stats_s[4] = (float)C;
    }
    __syncthreads();
    const float A0 = stats_s[0], A1 = stats_s[1], A2 = stats_s[2],
                A3 = stats_s[3], Cc = stats_s[4];
    const int b = blockIdx.x * 256 + tid;
    if (b < B) {
        float4 e = e4[b];
        out[b] = fmaf(e.x, A0, fmaf(e.y, A1, fmaf(e.z, A2, fmaf(e.w, A3, Cc))));
    }
}

// ---------------------------------------------------------------------------
extern "C" void kernel_launch(void* const* d_in, const int* in_sizes, int n_in,
                              void* d_out, int out_size, void* d_ws, size_t ws_size,
                              hipStream_t stream) {
    const float* x   = (const float*)d_in[0];
    const float* c1w = (const float*)d_in[1];
    const float* c1b = (const float*)d_in[2];
    const float* c2w = (const float*)d_in[3];
    const float* c2b = (const float*)d_in[4];
    const float* fcw = (const float*)d_in[5];
    const float* fcb = (const float*)d_in[6];
    const float* qrx = (const float*)d_in[7];
    const float* qry = (const float*)d_in[8];
    const float* qrz = (const float*)d_in[9];
    const float* rl  = (const float*)d_in[10];
    const float* gmm = (const float*)d_in[11];
    const float* bta = (const float*)d_in[12];
    const float* ow  = (const float*)d_in[13];
    const float* ob  = (const float*)d_in[14];
    float* out = (float*)d_out;
    const int B = in_sizes[0] / 784;
    if (B <= 0) return;

    float* ws   = (float*)d_ws;
    float* U    = ws;                       // 512 floats
    float* exps = ws + 512;                 // B*4 floats (16B aligned)

    Ops37 ops;
    build_ops_host(&ops);

    build_u_kernel<<<dim3(1), dim3(64), 0, stream>>>(rl, qrx, qry, qrz, U, ops);
    fused_fwd_kernel<<<dim3(B), dim3(128), 0, stream>>>(
        x, c1w, c1b, c2w, c2b, fcw, fcb, U, exps);
    out_all_kernel<<<dim3((B + 255) / 256), dim3(256), 0, stream>>>(
        exps, gmm, bta, ow, ob, out, B);
}

// Round 16
// 144.181 us; speedup vs baseline: 1.0482x; 1.0482x over previous
//
#include <hip/hip_runtime.h>
#include <stdint.h>
#include <math.h>

#define NOPS 37

struct Ops37 {
    int type[NOPS];  // 0 rx, 1 ry, 2 rz, 3 cnot, 4 H, 5 SX
    int a[NOPS];     // wire (rot/H/SX) or control (cnot)
    int b[NOPS];     // target (cnot), else -1
};

// ---------------------------------------------------------------------------
// Host-side exact replication of np.random.default_rng(42) for _random_ops().
// VERIFIED PASSING (round 3). DO NOT TOUCH.
// ---------------------------------------------------------------------------
static void build_ops_host(Ops37* ops) {
    uint32_t pool[4];
    uint32_t hc = 0x43b0d7e5u;  // INIT_A
    auto hmix = [&hc](uint32_t value) -> uint32_t {
        value ^= hc;
        hc *= 0x931e8875u;      // MULT_A
        value *= hc;
        value ^= value >> 16;
        return value;
    };
    auto mixf = [](uint32_t x, uint32_t y) -> uint32_t {
        uint32_t r = (x * 0xca01f9ddu) - (y * 0x4973f715u);  // SUBTRACTION
        r ^= r >> 16;
        return r;
    };
    pool[0] = hmix(42u);
    for (int i = 1; i < 4; i++) pool[i] = hmix(0u);
    for (int s = 0; s < 4; s++)
        for (int d = 0; d < 4; d++)
            if (s != d) pool[d] = mixf(pool[d], hmix(pool[s]));

    uint32_t st[8];
    {
        uint32_t hcb = 0x8b51f9ddu;  // INIT_B
        for (int i = 0; i < 8; i++) {
            uint32_t dv = pool[i & 3];
            dv ^= hcb;
            hcb *= 0x58f38dedu;      // MULT_B
            dv *= hcb;
            dv ^= dv >> 16;
            st[i] = dv;
        }
    }
    typedef __uint128_t u128;
    const uint64_t v0 = (uint64_t)st[0] | ((uint64_t)st[1] << 32);
    const uint64_t v1 = (uint64_t)st[2] | ((uint64_t)st[3] << 32);
    const uint64_t v2 = (uint64_t)st[4] | ((uint64_t)st[5] << 32);
    const uint64_t v3 = (uint64_t)st[6] | ((uint64_t)st[7] << 32);
    const u128 initstate = (((u128)v0) << 64) | v1;
    const u128 initseq   = (((u128)v2) << 64) | v3;
    const u128 MULT = (((u128)0x2360ed051fc65da4ULL) << 64) | 0x4385df649fccf645ULL;

    u128 state = 0;
    const u128 inc = (initseq << 1) | 1;
    state = state * MULT + inc;
    state += initstate;
    state = state * MULT + inc;

    bool has32 = false;
    uint32_t cached = 0;
    auto next64 = [&]() -> uint64_t {
        state = state * MULT + inc;
        uint64_t hi = (uint64_t)(state >> 64);
        uint64_t lo = (uint64_t)state;
        unsigned rot = (unsigned)(state >> 122) & 63u;
        uint64_t v = hi ^ lo;
        return (v >> rot) | (v << ((64u - rot) & 63u));
    };
    auto next32 = [&]() -> uint32_t {
        if (has32) { has32 = false; return cached; }
        uint64_t n = next64();
        has32 = true;
        cached = (uint32_t)(n >> 32);
        return (uint32_t)n;
    };
    auto lem = [&](uint32_t rng) -> uint32_t {
        const uint32_t rng_excl = rng + 1u;
        uint64_t m = (uint64_t)next32() * (uint64_t)rng_excl;
        uint32_t leftover = (uint32_t)m;
        if (leftover < rng_excl) {
            const uint32_t threshold = (0xFFFFFFFFu - rng) % rng_excl;
            while (leftover < threshold) {
                m = (uint64_t)next32() * (uint64_t)rng_excl;
                leftover = (uint32_t)m;
            }
        }
        return (uint32_t)(m >> 32);
    };

    for (int k = 0; k < 30; k++) {
        uint32_t g = lem(3);
        if (g == 3u) {
            uint32_t i0 = lem(2);
            uint32_t vv = lem(3);
            uint32_t i1 = (vv == i0) ? 3u : vv;
            uint32_t j = lem(1);
            if (j == 0u) { uint32_t t = i0; i0 = i1; i1 = t; }
            ops->type[k] = 3; ops->a[k] = (int)i0; ops->b[k] = (int)i1;
        } else {
            uint32_t w = lem(3);
            ops->type[k] = (int)g; ops->a[k] = (int)w; ops->b[k] = -1;
        }
    }
    ops->type[30] = 0; ops->a[30] = 0; ops->b[30] = -1;
    ops->type[31] = 1; ops->a[31] = 1; ops->b[31] = -1;
    ops->type[32] = 2; ops->a[32] = 2; ops->b[32] = -1;
    ops->type[33] = 3; ops->a[33] = 0; ops->b[33] = 3;
    ops->type[34] = 4; ops->a[34] = 3; ops->b[34] = -1;
    ops->type[35] = 5; ops->a[35] = 2; ops->b[35] = -1;
    ops->type[36] = 3; ops->a[36] = 3; ops->b[36] = 0;
}

// ---------------------------------------------------------------------------
// Kernel 0: build the fixed 16x16 unitary U (post-encoding circuit). fp32.
// ---------------------------------------------------------------------------
__global__ __launch_bounds__(64) void build_u_kernel(
        const float* __restrict__ rl, const float* __restrict__ qrx,
        const float* __restrict__ qry, const float* __restrict__ qrz,
        float* __restrict__ Uout, Ops37 ops) {
    int j = threadIdx.x;
    if (j >= 16) return;
    float cr[16], ci[16];
    for (int i = 0; i < 16; i++) { cr[i] = (i == j) ? 1.f : 0.f; ci[i] = 0.f; }
    for (int k = 0; k < NOPS; k++) {
        int t = ops.type[k];
        if (t == 3) {
            int mc = 8 >> ops.a[k], mt = 8 >> ops.b[k];
            for (int i = 0; i < 16; i++) {
                if ((i & mc) && !(i & mt)) {
                    int i2 = i | mt;
                    float tr = cr[i], ti = ci[i];
                    cr[i] = cr[i2]; ci[i] = ci[i2];
                    cr[i2] = tr;    ci[i2] = ti;
                }
            }
        } else {
            float g00r, g00i, g01r, g01i, g10r, g10i, g11r, g11i;
            if (t == 4) {
                const float r = 0.70710678118654752440f;
                g00r = r; g00i = 0; g01r = r;  g01i = 0;
                g10r = r; g10i = 0; g11r = -r; g11i = 0;
            } else if (t == 5) {
                g00r = 0.5f; g00i = 0.5f;  g01r = 0.5f; g01i = -0.5f;
                g10r = 0.5f; g10i = -0.5f; g11r = 0.5f; g11i = 0.5f;
            } else {
                float th = (k < 30) ? rl[k]
                         : (k == 30 ? qrx[0] : (k == 31 ? qry[0] : qrz[0]));
                float c = cosf(0.5f * th), s = sinf(0.5f * th);
                if (t == 0) {
                    g00r = c; g00i = 0;  g01r = 0; g01i = -s;
                    g10r = 0; g10i = -s; g11r = c; g11i = 0;
                } else if (t == 1) {
                    g00r = c; g00i = 0; g01r = -s; g01i = 0;
                    g10r = s; g10i = 0; g11r = c;  g11i = 0;
                } else {
                    g00r = c; g00i = -s; g01r = 0; g01i = 0;
                    g10r = 0; g10i = 0;  g11r = c; g11i = s;
                }
            }
            int m = 8 >> ops.a[k];
            for (int i = 0; i < 16; i++) {
                if (!(i & m)) {
                    int i2 = i | m;
                    float ar = cr[i], ai = ci[i], br = cr[i2], bi = ci[i2];
                    cr[i]  = g00r * ar - g00i * ai + g01r * br - g01i * bi;
                    ci[i]  = g00r * ai + g00i * ar + g01r * bi + g01i * br;
                    cr[i2] = g10r * ar - g10i * ai + g11r * br - g11i * bi;
                    ci[i2] = g10r * ai + g10i * ar + g11r * bi + g11i * br;
                }
            }
        }
    }
    for (int i = 0; i < 16; i++) {
        Uout[2 * (i * 16 + j)]     = cr[i];
        Uout[2 * (i * 16 + j) + 1] = ci[i];
    }
}

// ---------------------------------------------------------------------------
// Kernel 1: fused per-sample forward. EXACT round-13 kernel (97us, 48 VGPR,
// conflicts 5.2e5, VALUBusy 72%). This is the proven-best configuration:
// r14 pkfma (neutral-worse) and r15 merged-tail (regression) both reverted.
// Busy-time invariant (r10-r15): VALU busy ~70us regardless of occupancy —
// issue-count-bound; remaining levers all measured worse.
// LDS (floats): XP 30x34 [0,1020) reused as h2[784]; H1 8x292 [1020,3356);
// RED[8] FEAT[4] PSI[32] PV[16]. 13.7 KB -> 11 blocks/CU.
// ---------------------------------------------------------------------------
#define XPo   0
#define H2o   0
#define H1o   1020
#define REDo  3356
#define FEATo 3364
#define PSIo  3368
#define PVo   3400
#define SMSZ  3416

#define H1CS  292   // channel stride (= 4 mod 32)
#define H1RS  18    // row stride (bank start 4*py, 7 distinct)

__global__ __launch_bounds__(128) void fused_fwd_kernel(
        const float* __restrict__ x,
        const float* __restrict__ c1w, const float* __restrict__ c1b,
        const float* __restrict__ c2w, const float* __restrict__ c2b,
        const float* __restrict__ fcw, const float* __restrict__ fcb,
        const float* __restrict__ Ug, float* __restrict__ exps) {
    __shared__ __align__(16) float SM[SMSZ];
    const int tid = threadIdx.x;
    const int bidx = blockIdx.x;

    // ---- stage x (zero-padded 30x34); zero H1 borders only ----
    {
        const float* xb = x + (size_t)bidx * 784;
        for (int i = tid; i < 1020; i += 128) {
            int r = i / 34, c = i - r * 34;
            float v = 0.f;
            if (r >= 1 && r <= 28 && c >= 1 && c <= 28) v = xb[(r - 1) * 28 + (c - 1)];
            SM[XPo + i] = v;
        }
    }
    for (int i = tid; i < 480; i += 128) {
        int ch = i / 60, j = i - ch * 60;
        int row, col;
        if (j < 16)      { row = 0;  col = j; }
        else if (j < 32) { row = 15; col = j - 16; }
        else             { row = 1 + ((j - 32) >> 1); col = ((j - 32) & 1) * 15; }
        SM[H1o + ch * H1CS + row * H1RS + col] = 0.f;
    }
    __syncthreads();

    // ---- conv1 + relu + pool ----
    {
        const int c    = tid & 7;
        const int pos0 = tid >> 3;
        float wv[9];
        #pragma unroll
        for (int t = 0; t < 9; t++) wv[t] = c1w[c * 9 + t];
        const float bb = c1b[c];
        for (int pos = pos0; pos < 98; pos += 16) {
            int py = pos / 7, pxp = pos - py * 7;
            float P[4][6];
            #pragma unroll
            for (int r = 0; r < 4; r++) {
                const float2 a  = *(const float2*)&SM[XPo + (2 * py + r) * 34 + 4 * pxp];
                const float2 b_ = *(const float2*)&SM[XPo + (2 * py + r) * 34 + 4 * pxp + 2];
                const float2 c_ = *(const float2*)&SM[XPo + (2 * py + r) * 34 + 4 * pxp + 4];
                P[r][0] = a.x; P[r][1] = a.y; P[r][2] = b_.x;
                P[r][3] = b_.y; P[r][4] = c_.x; P[r][5] = c_.y;
            }
            #pragma unroll
            for (int half = 0; half < 2; half++) {
                float m = -3.4e38f;
                #pragma unroll
                for (int dy = 0; dy < 2; dy++)
                    #pragma unroll
                    for (int dx = 0; dx < 2; dx++) {
                        float acc = 0.f;
                        #pragma unroll
                        for (int ky = 0; ky < 3; ky++)
                            #pragma unroll
                            for (int kx = 0; kx < 3; kx++)
                                acc = fmaf(P[dy + ky][2 * half + dx + kx], wv[ky * 3 + kx], acc);
                        m = fmaxf(m, acc);
                    }
                SM[H1o + c * H1CS + (py + 1) * H1RS + (2 * pxp + half + 1)] = fmaxf(m + bb, 0.f);
            }
        }
    }
    __syncthreads();

    // ---- conv2 + relu + pool ----
    if (tid < 112) {
        int c2 = tid / 7, py = tid - (tid / 7) * 7;
        float acc[7][4];
        #pragma unroll
        for (int px = 0; px < 7; px++)
            #pragma unroll
            for (int s = 0; s < 4; s++) acc[px][s] = 0.f;
        for (int c1 = 0; c1 < 8; c1++) {   // rolled: keeps VGPR ~48
            float R[4][16];
            #pragma unroll
            for (int r = 0; r < 4; r++) {
                #pragma unroll
                for (int q = 0; q < 8; q++) {
                    const float2 v = *(const float2*)&SM[H1o + c1 * H1CS + (2 * py + r) * H1RS + 2 * q];
                    R[r][2 * q] = v.x; R[r][2 * q + 1] = v.y;
                }
            }
            float w[9];
            #pragma unroll
            for (int t = 0; t < 9; t++) w[t] = c2w[(c2 * 8 + c1) * 9 + t];
            #pragma unroll
            for (int px = 0; px < 7; px++)
                #pragma unroll
                for (int dy = 0; dy < 2; dy++)
                    #pragma unroll
                    for (int dx = 0; dx < 2; dx++) {
                        float a = acc[px][dy * 2 + dx];
                        #pragma unroll
                        for (int ky = 0; ky < 3; ky++)
                            #pragma unroll
                            for (int kx = 0; kx < 3; kx++)
                                a = fmaf(R[dy + ky][2 * px + dx + kx], w[ky * 3 + kx], a);
                        acc[px][dy * 2 + dx] = a;
                    }
        }
        const float bb = c2b[c2];
        #pragma unroll
        for (int px = 0; px < 7; px++) {
            float m = fmaxf(fmaxf(acc[px][0], acc[px][1]), fmaxf(acc[px][2], acc[px][3]));
            SM[H2o + c2 * 49 + py * 7 + px] = fmaxf(m + bb, 0.f);
        }
    }
    __syncthreads();

    // ---- fc rows 0..3: shfl reduction ----
    {
        float a0 = 0.f, a1 = 0.f, a2 = 0.f, a3 = 0.f;
        for (int j = tid; j < 784; j += 128) {
            float h = SM[H2o + j];
            a0 = fmaf(h, fcw[j],        a0);
            a1 = fmaf(h, fcw[784 + j],  a1);
            a2 = fmaf(h, fcw[1568 + j], a2);
            a3 = fmaf(h, fcw[2352 + j], a3);
        }
        #pragma unroll
        for (int off = 32; off > 0; off >>= 1) {
            a0 += __shfl_down(a0, off);
            a1 += __shfl_down(a1, off);
            a2 += __shfl_down(a2, off);
            a3 += __shfl_down(a3, off);
        }
        if ((tid & 63) == 0) {
            int wid = tid >> 6;
            SM[REDo + wid * 4 + 0] = a0;
            SM[REDo + wid * 4 + 1] = a1;
            SM[REDo + wid * 4 + 2] = a2;
            SM[REDo + wid * 4 + 3] = a3;
        }
    }
    __syncthreads();
    if (tid < 4)
        SM[FEATo + tid] = fmaxf(SM[REDo + tid] + SM[REDo + 4 + tid] + fcb[tid], 0.f);
    __syncthreads();

    // ---- quantum circuit ----
    if (tid < 16) {
        int j = tid;
        float re = 1.f, im = 0.f;
        #pragma unroll
        for (int w = 0; w < 4; w++) {
            float half = 0.5f * SM[FEATo + w];
            float cc = cosf(half), ss = sinf(half);
            if ((j >> (3 - w)) & 1) {
                float nr = ss * im, ni = -ss * re;
                re = nr; im = ni;
            } else {
                re *= cc; im *= cc;
            }
        }
        SM[PSIo + 2 * j] = re; SM[PSIo + 2 * j + 1] = im;
    }
    __syncthreads();
    if (tid < 16) {
        int r = tid;
        float ar = 0.f, ai = 0.f;
        const float2* U2 = (const float2*)Ug;
        #pragma unroll
        for (int j2 = 0; j2 < 16; j2++) {
            float2 u = U2[r * 16 + j2];
            float pr = SM[PSIo + 2 * j2], pi = SM[PSIo + 2 * j2 + 1];
            ar += u.x * pr - u.y * pi;
            ai += u.x * pi + u.y * pr;
        }
        SM[PVo + r] = ar * ar + ai * ai;
    }
    __syncthreads();
    if (tid < 4) {
        int w = tid, msk = 8 >> w;
        float e = 0.f;
        #pragma unroll
        for (int r = 0; r < 16; r++) {
            float p = SM[PVo + r];
            e += (r & msk) ? -p : p;
        }
        exps[(size_t)bidx * 4 + w] = e;
    }
}

// ---------------------------------------------------------------------------
// Kernel 2: partial BN stats, 16 blocks x 256, distinct output slots.
// (r15 lesson: merging this into one redundant-reduce kernel LOSES — the
// redundant full reduction's 32-iteration latency chain > dispatch cost.)
// ---------------------------------------------------------------------------
#define NPART 16
__global__ __launch_bounds__(256) void bn_part_kernel(
        const float* __restrict__ exps, double* __restrict__ partials, int B) {
    const int tid = threadIdx.x, blk = blockIdx.x;
    const int chunk = (B + NPART - 1) / NPART;
    const int lo = blk * chunk, hi = min(B, lo + chunk);
    double s0 = 0, s1 = 0, s2 = 0, s3 = 0, q0 = 0, q1 = 0, q2 = 0, q3 = 0;
    const float4* e4 = (const float4*)exps;
    for (int i = lo + tid; i < hi; i += 256) {
        float4 e = e4[i];
        s0 += e.x; q0 += (double)e.x * e.x;
        s1 += e.y; q1 += (double)e.y * e.y;
        s2 += e.z; q2 += (double)e.z * e.z;
        s3 += e.w; q3 += (double)e.w * e.w;
    }
    __shared__ double red[8][256];
    red[0][tid] = s0; red[1][tid] = s1; red[2][tid] = s2; red[3][tid] = s3;
    red[4][tid] = q0; red[5][tid] = q1; red[6][tid] = q2; red[7][tid] = q3;
    __syncthreads();
    for (int st = 128; st > 0; st >>= 1) {
        if (tid < st)
            for (int k = 0; k < 8; k++) red[k][tid] += red[k][tid + st];
        __syncthreads();
    }
    if (tid < 8) partials[blk * 8 + tid] = red[tid][0];
}

// ---------------------------------------------------------------------------
// Kernel 3: final output, 1 sample/thread; each block redundantly reduces
// the 16x8 partials in fixed order (deterministic, no atomics).
// ---------------------------------------------------------------------------
__global__ __launch_bounds__(256) void out_final_kernel(
        const float* __restrict__ exps, const double* __restrict__ partials,
        const float* __restrict__ gamma, const float* __restrict__ beta,
        const float* __restrict__ ow, const float* __restrict__ ob,
        float* __restrict__ out, int B) {
    const int tid = threadIdx.x;
    __shared__ double red8[8];
    __shared__ float stats_s[5];
    if (tid < 8) {
        double s = 0.0;
        for (int j = 0; j < NPART; j++) s += partials[j * 8 + tid];
        red8[tid] = s;
    }
    __syncthreads();
    if (tid == 0) {
        double C = (double)ob[0];
        for (int w = 0; w < 4; w++) {
            double mean = red8[w] / (double)B;
            double var  = red8[4 + w] / (double)B - mean * mean;
            double inv  = 1.0 / sqrt(var + 1e-5);
            double scale = (double)gamma[w] * inv;
            stats_s[w] = (float)(scale * (double)ow[w]);
            C += ((double)beta[w] - mean * scale) * (double)ow[w];
        }
        stats_s[4] = (float)C;
    }
    __syncthreads();
    const float A0 = stats_s[0], A1 = stats_s[1], A2 = stats_s[2],
                A3 = stats_s[3], Cc = stats_s[4];
    const int b = blockIdx.x * 256 + tid;
    if (b < B) {
        float4 e = reinterpret_cast<const float4*>(exps)[b];
        out[b] = fmaf(e.x, A0, fmaf(e.y, A1, fmaf(e.z, A2, fmaf(e.w, A3, Cc))));
    }
}

// ---------------------------------------------------------------------------
extern "C" void kernel_launch(void* const* d_in, const int* in_sizes, int n_in,
                              void* d_out, int out_size, void* d_ws, size_t ws_size,
                              hipStream_t stream) {
    const float* x   = (const float*)d_in[0];
    const float* c1w = (const float*)d_in[1];
    const float* c1b = (const float*)d_in[2];
    const float* c2w = (const float*)d_in[3];
    const float* c2b = (const float*)d_in[4];
    const float* fcw = (const float*)d_in[5];
    const float* fcb = (const float*)d_in[6];
    const float* qrx = (const float*)d_in[7];
    const float* qry = (const float*)d_in[8];
    const float* qrz = (const float*)d_in[9];
    const float* rl  = (const float*)d_in[10];
    const float* gmm = (const float*)d_in[11];
    const float* bta = (const float*)d_in[12];
    const float* ow  = (const float*)d_in[13];
    const float* ob  = (const float*)d_in[14];
    float* out = (float*)d_out;
    const int B = in_sizes[0] / 784;
    if (B <= 0) return;

    float*  ws       = (float*)d_ws;
    float*  U        = ws;                          // 512 floats
    float*  exps     = ws + 512;                    // B*4 floats (16B aligned)
    double* partials = (double*)(ws + 512 + 4 * (size_t)B);  // 16*8 doubles

    Ops37 ops;
    build_ops_host(&ops);

    build_u_kernel<<<dim3(1), dim3(64), 0, stream>>>(rl, qrx, qry, qrz, U, ops);
    fused_fwd_kernel<<<dim3(B), dim3(128), 0, stream>>>(
        x, c1w, c1b, c2w, c2b, fcw, fcb, U, exps);
    bn_part_kernel<<<dim3(NPART), dim3(256), 0, stream>>>(exps, partials, B);
    out_final_kernel<<<dim3((B + 255) / 256), dim3(256), 0, stream>>>(
        exps, partials, gmm, bta, ow, ob, out, B);
}